// Round 4
// baseline (433.175 us; speedup 1.0000x reference)
//
#include <hip/hip_runtime.h>
#include <math.h>

#define NN   131072
#define CN   128
#define BN   64
#define NPGN 2048
#define MN   64
#define EN   1048576

typedef unsigned short u16;
typedef unsigned int   u32;
typedef __attribute__((ext_vector_type(8))) short short8;
typedef __attribute__((ext_vector_type(4))) float f32x4;

__device__ __forceinline__ float bf2f(u16 u){ return __uint_as_float(((u32)u)<<16); }
__device__ __forceinline__ u16 f2bf(float f){
  u32 x = __float_as_uint(f);
  return (u16)((x + 0x7fffu + ((x>>16)&1u)) >> 16);
}

// ---------------- graph build ----------------
__global__ void k_count(const int* __restrict__ dst, int* __restrict__ deg){
  int e = blockIdx.x*256 + threadIdx.x;
  atomicAdd(&deg[dst[e]], 1);
}

__global__ void k_scan1(const int* __restrict__ deg, int* __restrict__ rowst, int* __restrict__ bsum){
  __shared__ int s[512];
  const int t = threadIdx.x;
  const int i = blockIdx.x*512 + t;
  int v = deg[i];
  s[t] = v;
  __syncthreads();
  for (int off=1; off<512; off<<=1){
    int a = (t>=off) ? s[t-off] : 0;
    __syncthreads();
    s[t] += a;
    __syncthreads();
  }
  rowst[i] = s[t] - v;
  if (t==511) bsum[blockIdx.x] = s[511];
}

__global__ void k_scan2(const int* __restrict__ bsum, int* __restrict__ bofs){
  __shared__ int s[256];
  const int t = threadIdx.x;
  int v = bsum[t];
  s[t] = v;
  __syncthreads();
  for (int off=1; off<256; off<<=1){
    int a = (t>=off) ? s[t-off] : 0;
    __syncthreads();
    s[t] += a;
    __syncthreads();
  }
  bofs[t] = s[t] - v;
}

__global__ void k_scan3(int* __restrict__ rowst, const int* __restrict__ bofs){
  int i = blockIdx.x*256 + threadIdx.x;
  rowst[i] += bofs[i>>9];
}

__global__ void k_fill(const int* __restrict__ src, const int* __restrict__ dst,
                       const int* __restrict__ rowst, int* __restrict__ cursor,
                       int* __restrict__ csr){
  int e = blockIdx.x*256 + threadIdx.x;
  int d = dst[e];
  int p = atomicAdd(&cursor[d], 1);
  csr[rowst[d] + p] = src[e];
}

// ---------------- weight prep: B-fragment-swizzled bf16 lin_w (round-4 validated) ----------------
__global__ void k_prepw(const float* __restrict__ lin_w, u16* __restrict__ wsw){
  int tid = blockIdx.x*256 + threadIdx.x;   // 2048 total
  int g = tid >> 6, L = tid & 63;
  int ct = g >> 2, ks = g & 3;
  int o = L & 15, q = L >> 4;
  const float* srcp = lin_w + (ct*16+o)*CN + ks*32 + q*8;
  u16 tmp[8];
  #pragma unroll
  for (int j=0;j<8;++j) tmp[j] = f2bf(srcp[j]);
  *(uint4*)(wsw + (size_t)tid*8) = *(const uint4*)tmp;
}

// ---------------- weight prep: W[m][c][o] fp32 -> WT16[m][o][c] bf16 ----------------
__global__ void k_prepWT(const float* __restrict__ W, u16* __restrict__ WT16){
  __shared__ u16 st[128*132];    // 33.8 KB
  const int t = threadIdx.x;
  const int m = blockIdx.x;
  const float* Wm = W + (size_t)m*CN*CN;
  #pragma unroll
  for (int it=0; it<16; ++it){
    int flat = (it*256 + t)*4;
    int c = flat >> 7, o = flat & 127;
    float4 v = *(const float4*)(Wm + flat);
    st[(o+0)*132 + c] = f2bf(v.x);
    st[(o+1)*132 + c] = f2bf(v.y);
    st[(o+2)*132 + c] = f2bf(v.z);
    st[(o+3)*132 + c] = f2bf(v.w);
  }
  __syncthreads();
  u16* dstm = WT16 + (size_t)m*CN*CN;
  #pragma unroll
  for (int it=0; it<8; ++it){
    int oidx = (it*256 + t)*8;
    int o = oidx >> 7, c = oidx & 127;
    uint4 v = *(const uint4*)&st[o*132 + c];
    *(uint4*)(dstm + (size_t)o*CN + c) = v;
  }
}

// ---------------- prep: h fp32 -> h16 natural bf16 + ht16[b][c][n] bf16 ----------------
// grid 64*32, 256 thr; tile = 64 n-rows x 128 c
__global__ void k_prep_h(const float* __restrict__ h, u16* __restrict__ h16, u16* __restrict__ ht16){
  __shared__ u16 st[CN*72];   // st[c*72 + r], r<64
  const int t = threadIdx.x;
  const int b = blockIdx.x >> 5;
  const int n0 = (blockIdx.x & 31)*64;
  const float* srcb = h + ((size_t)b*NPGN + n0)*CN;
  u16* natb = h16 + ((size_t)b*NPGN + n0)*CN;
  #pragma unroll
  for (int j=0;j<8;++j){
    int fidx = (j*256+t)*4;
    int r = fidx>>7, c = fidx&127;
    float4 v = *(const float4*)(srcb + fidx);
    u16 q0=f2bf(v.x), q1=f2bf(v.y), q2=f2bf(v.z), q3=f2bf(v.w);
    ushort4 nv; nv.x=q0; nv.y=q1; nv.z=q2; nv.w=q3;
    *(ushort4*)(natb + fidx) = nv;
    st[(c+0)*72 + r] = q0; st[(c+1)*72 + r] = q1;
    st[(c+2)*72 + r] = q2; st[(c+3)*72 + r] = q3;
  }
  __syncthreads();
  #pragma unroll
  for (int j=0;j<4;++j){
    int oidx = (j*256+t)*8;
    int c = oidx>>6, nn = oidx&63;
    uint4 v = *(const uint4*)&st[c*72 + nn];
    *(uint4*)(ht16 + ((size_t)b*CN + c)*NPGN + n0 + nn) = v;
  }
}

// ---------------- prep: U fp32 -> U16 natural bf16 + Ut16[b][m][n] bf16 ----------------
// grid 64*16, 256 thr; tile = 128 n-rows x 64 m
__global__ void k_prep_U(const float* __restrict__ U, u16* __restrict__ U16, u16* __restrict__ Ut16){
  __shared__ u16 st2[MN*136];   // st2[m*136 + r], r<128
  const int t = threadIdx.x;
  const int b = blockIdx.x >> 4;
  const int n0 = (blockIdx.x & 15)*128;
  const float* srcb = U + ((size_t)b*NPGN + n0)*MN;
  u16* natb = U16 + ((size_t)b*NPGN + n0)*MN;
  #pragma unroll
  for (int j=0;j<8;++j){
    int fidx = (j*256+t)*4;
    int r = fidx>>6, mm = fidx&63;
    float4 v = *(const float4*)(srcb + fidx);
    u16 q0=f2bf(v.x), q1=f2bf(v.y), q2=f2bf(v.z), q3=f2bf(v.w);
    ushort4 nv; nv.x=q0; nv.y=q1; nv.z=q2; nv.w=q3;
    *(ushort4*)(natb + fidx) = nv;
    st2[(mm+0)*136 + r] = q0; st2[(mm+1)*136 + r] = q1;
    st2[(mm+2)*136 + r] = q2; st2[(mm+3)*136 + r] = q3;
  }
  __syncthreads();
  #pragma unroll
  for (int j=0;j<4;++j){
    int oidx = (j*256+t)*8;
    int mm = oidx>>7, nn = oidx&127;
    uint4 v = *(const uint4*)&st2[mm*136 + nn];
    *(uint4*)(Ut16 + ((size_t)b*MN + mm)*NPGN + n0 + nn) = v;
  }
}

// ---------------- h_hat partials (MFMA): hp[q][b][m][c], K-chunk 256, c-half per block ----------------
// C[m][c] = sum_n Ut16[b][m][n] * ht16[b][c][n]; grid 64*8*2, 4 waves, wave = m-tile
__global__ __launch_bounds__(256) void k_hhat(const u16* __restrict__ Ut16,
                                              const u16* __restrict__ ht16,
                                              float* __restrict__ hp){
  const int t = threadIdx.x;
  const int L = t & 63, w = t >> 6;
  const int b  = blockIdx.x >> 4;
  const int q  = (blockIdx.x >> 1) & 7;
  const int ch = blockIdx.x & 1;            // c-half
  const int lo = L & 15, qd = (L >> 4) << 3;
  f32x4 acc[4] = {};
  const u16* Arow  = Ut16 + ((size_t)(b*MN + w*16 + lo))*NPGN + q*256 + qd;
  const u16* Bbase = ht16 + ((size_t)(b*CN + ch*64 + lo))*NPGN + q*256 + qd;
  #pragma unroll
  for (int ks=0; ks<8; ++ks){
    short8 af = *(const short8*)(Arow + ks*32);
    #pragma unroll
    for (int ct=0; ct<4; ++ct){
      short8 bf = *(const short8*)(Bbase + (size_t)ct*16*NPGN + ks*32);
      acc[ct] = __builtin_amdgcn_mfma_f32_16x16x32_bf16(af, bf, acc[ct], 0, 0, 0);
    }
  }
  const int rb = w*16 + ((L>>4)<<2);
  float* dstb = hp + ((size_t)q*BN + b)*MN*CN;
  #pragma unroll
  for (int ct=0; ct<4; ++ct)
    #pragma unroll
    for (int r=0; r<4; ++r)
      dstb[(size_t)(rb+r)*CN + ch*64 + ct*16 + lo] = acc[ct][r];
}

// ---------------- out_hat (MFMA): ohatT[b][o][m] = bf16( sum_c hh[b,c]*W[m,c,o] ) ----------------
// grid 64m*4bq, 256 thr (4 waves). hh = sum_q hp, hi/lo bf16 split for fp32 fidelity.
__global__ __launch_bounds__(256) void k_ohat(const float* __restrict__ hp,
                                              const u16* __restrict__ WT16,
                                              u16* __restrict__ ohatT){
  __shared__ u16 shHi[16*132];   // 4.2 KB
  __shared__ u16 shLo[16*132];   // 4.2 KB
  const int t = threadIdx.x;
  const int m  = blockIdx.x >> 2;
  const int bq = blockIdx.x & 3;       // b-quarter: rows bq*16 .. bq*16+15

  // Stage 1: hh[bl][c] = sum_q hp[q][bq*16+bl][m][c]; split into hi/lo bf16
  {
    const int bl = t >> 4;             // 0..15
    const int c0 = (t & 15) * 8;       // 8 channels
    const size_t S = (size_t)BN*MN*CN;
    const float* base = hp + ((size_t)(bq*16 + bl)*MN + m)*CN + c0;
    float a[8] = {0,0,0,0,0,0,0,0};
    #pragma unroll
    for (int q=0; q<8; ++q){
      float4 v0 = *(const float4*)(base + q*S);
      float4 v1 = *(const float4*)(base + q*S + 4);
      a[0]+=v0.x; a[1]+=v0.y; a[2]+=v0.z; a[3]+=v0.w;
      a[4]+=v1.x; a[5]+=v1.y; a[6]+=v1.z; a[7]+=v1.w;
    }
    u16 hi[8], lo[8];
    #pragma unroll
    for (int j=0;j<8;++j){
      hi[j] = f2bf(a[j]);
      lo[j] = f2bf(a[j] - bf2f(hi[j]));
    }
    *(uint4*)&shHi[bl*132 + c0] = *(const uint4*)hi;
    *(uint4*)&shLo[bl*132 + c0] = *(const uint4*)lo;
  }
  __syncthreads();

  // Stage 2: wave w -> o-range w*32..w*32+31 (2 o-tiles), K=128 (4 ks), hi+lo MFMA
  const int L = t & 63, w = t >> 6;
  const int lo16 = L & 15, qd = (L >> 4) << 3;
  const u16* WTm = WT16 + (size_t)m*CN*CN;
  f32x4 acc[2] = {};
  #pragma unroll
  for (int ks=0; ks<4; ++ks){
    short8 ah = *(const short8*)&shHi[lo16*132 + ks*32 + qd];
    short8 al = *(const short8*)&shLo[lo16*132 + ks*32 + qd];
    #pragma unroll
    for (int ot=0; ot<2; ++ot){
      short8 bf = *(const short8*)(WTm + (size_t)(w*32 + ot*16 + lo16)*CN + ks*32 + qd);
      acc[ot] = __builtin_amdgcn_mfma_f32_16x16x32_bf16(ah, bf, acc[ot], 0, 0, 0);
      acc[ot] = __builtin_amdgcn_mfma_f32_16x16x32_bf16(al, bf, acc[ot], 0, 0, 0);
    }
  }
  const int rb = (L>>4)<<2;
  #pragma unroll
  for (int ot=0; ot<2; ++ot){
    #pragma unroll
    for (int r=0; r<4; ++r){
      int b = bq*16 + rb + r;
      int o = w*32 + ot*16 + lo16;
      ohatT[((size_t)b*CN + o)*MN + m] = f2bf(acc[ot][r]);
    }
  }
}

// ---------------- fused: gather-mean + (local+spec) MFMA + LN + GELU ----------------
__global__ __launch_bounds__(256,5) void k_localep(
    const u16* __restrict__ h16, const u16* __restrict__ U16,
    const u16* __restrict__ ohatT, const u16* __restrict__ wsw,
    const int* __restrict__ rowst, const int* __restrict__ deg, const int* __restrict__ csr,
    const float* __restrict__ lin_b, const float* __restrict__ ln_g,
    const float* __restrict__ ln_beta, float* __restrict__ out){
  __shared__ u16 sv[32*136];     // 8.7 KB  mean-neighbor rows (bf16, pitch 136)
  __shared__ u16 sx16[32*132];   // 8.4 KB  local+spec result (bf16)
  const int t = threadIdx.x;
  const int w = t>>6, lane = t&63;
  const size_t n0 = (size_t)blockIdx.x*32;

  // Phase A v3: wave w owns channel-quarter [w*32, w*32+32); lane = slot g (lane>>3)
  // x channel-octet c8 (lane&7, 4 channels = 8B). One idx-load covers 8 edges of a
  // node; two masked row-loads cover 16 edges (99.6% of Poisson(8) nodes); rare tail.
  // 32 independent node-iterations, unroll 4 => multiple load chains in flight.
  {
    const int g  = lane >> 3;
    const int c8 = lane & 7;
    const u16* hrow = h16 + w*32 + c8*4;
    #pragma unroll 4
    for (int i=0; i<32; ++i){
      const int node = (int)n0 + i;
      const int rs = rowst[node], dg = deg[node];
      const bool v1 = g < dg, v2 = g+8 < dg;
      int i1 = v1 ? csr[rs+g]   : 0;
      int i2 = v2 ? csr[rs+8+g] : 0;
      uint2 r1 = {0u,0u}, r2 = {0u,0u};
      if (v1) r1 = *(const uint2*)(hrow + (size_t)i1*CN);
      if (v2) r2 = *(const uint2*)(hrow + (size_t)i2*CN);
      float a0 = bf2f((u16)(r1.x&0xffffu)) + bf2f((u16)(r2.x&0xffffu));
      float a1 = bf2f((u16)(r1.x>>16))     + bf2f((u16)(r2.x>>16));
      float a2 = bf2f((u16)(r1.y&0xffffu)) + bf2f((u16)(r2.y&0xffffu));
      float a3 = bf2f((u16)(r1.y>>16))     + bf2f((u16)(r2.y>>16));
      if (__builtin_expect(dg > 16, 0)){
        for (int e = rs + 16 + g; e < rs + dg; e += 8){
          int ii = csr[e];
          uint2 r = *(const uint2*)(hrow + (size_t)ii*CN);
          a0 += bf2f((u16)(r.x&0xffffu)); a1 += bf2f((u16)(r.x>>16));
          a2 += bf2f((u16)(r.y&0xffffu)); a3 += bf2f((u16)(r.y>>16));
        }
      }
      // reduce over the 8 slots (lane bits 3,4,5)
      a0 += __shfl_xor(a0,8);  a1 += __shfl_xor(a1,8);  a2 += __shfl_xor(a2,8);  a3 += __shfl_xor(a3,8);
      a0 += __shfl_xor(a0,16); a1 += __shfl_xor(a1,16); a2 += __shfl_xor(a2,16); a3 += __shfl_xor(a3,16);
      a0 += __shfl_xor(a0,32); a1 += __shfl_xor(a1,32); a2 += __shfl_xor(a2,32); a3 += __shfl_xor(a3,32);
      const float inv = 1.0f / fmaxf((float)dg, 1.0f);
      if (g == 0){
        u32 p0 = (u32)f2bf(a0*inv) | ((u32)f2bf(a1*inv) << 16);
        u32 p1 = (u32)f2bf(a2*inv) | ((u32)f2bf(a3*inv) << 16);
        uint2 pk; pk.x = p0; pk.y = p1;
        *(uint2*)&sv[i*136 + w*32 + c8*4] = pk;
      }
    }
  }
  __syncthreads();

  // Phase B: acc = local (sv @ lin_w^T, K=128) + spec (U16 @ ohatT^T, K=64)
  // Both produce the same 32x128 output tile with identical C/D mapping.
  const int rt = w&1, cb = w>>1;
  const int lo16 = lane & 15, qd = (lane>>4)<<3;
  f32x4 acc[4] = {};
  #pragma unroll
  for (int ks=0; ks<4; ++ks){
    short8 af = *(const short8*)&sv[(rt*16 + lo16)*136 + ks*32 + qd];
    #pragma unroll
    for (int c4=0; c4<4; ++c4){
      const short8 bf = *(const short8*)(wsw + ((size_t)((cb*4+c4)*4+ks)*64 + lane)*8);
      acc[c4] = __builtin_amdgcn_mfma_f32_16x16x32_bf16(af, bf, acc[c4], 0, 0, 0);
    }
  }
  {
    const int b = (int)(n0 >> 11);                              // node block -> batch
    const u16* Au = U16  + ((size_t)(n0 + rt*16 + lo16))*MN + qd;
    const u16* Bu = ohatT + ((size_t)(b*CN + cb*64 + lo16))*MN + qd;
    #pragma unroll
    for (int ks=0; ks<2; ++ks){
      short8 af = *(const short8*)(Au + ks*32);
      #pragma unroll
      for (int c4=0; c4<4; ++c4){
        short8 bf = *(const short8*)(Bu + (size_t)c4*16*MN + ks*32);
        acc[c4] = __builtin_amdgcn_mfma_f32_16x16x32_bf16(af, bf, acc[c4], 0, 0, 0);
      }
    }
  }
  #pragma unroll
  for (int c4=0; c4<4; ++c4){
    int col = cb*64 + c4*16 + lo16;
    int rb = rt*16 + ((lane>>4)<<2);
    #pragma unroll
    for (int r=0; r<4; ++r) sx16[(rb+r)*132 + col] = f2bf(acc[c4][r]);
  }
  __syncthreads();

  // Phase C: x = h + (spec+local) + bias; LayerNorm; exact GELU
  float2 lb    = *(const float2*)(lin_b  + 2*lane);
  float2 lg    = *(const float2*)(ln_g   + 2*lane);
  float2 lbe   = *(const float2*)(ln_beta+ 2*lane);
  for (int r=0; r<8; ++r){
    int i = r*4 + w;
    size_t base = (n0 + i)*CN + 2*lane;
    u32 hA = *(const u32*)(h16 + base);
    u32 lA = *(const u32*)&sx16[i*132 + 2*lane];
    float x0 = bf2f((u16)(hA&0xffffu)) + bf2f((u16)(lA&0xffffu)) + lb.x;
    float x1 = bf2f((u16)(hA>>16))     + bf2f((u16)(lA>>16))     + lb.y;
    float s  = x0 + x1;
    float ss = fmaf(x0,x0, x1*x1);
    #pragma unroll
    for (int d=1; d<64; d<<=1){ s += __shfl_xor(s,d); ss += __shfl_xor(ss,d); }
    float mu  = s*(1.0f/128.0f);
    float var = ss*(1.0f/128.0f) - mu*mu;
    float rstd = rsqrtf(var + 1e-5f);
    float xn0 = (x0-mu)*rstd*lg.x + lbe.x;
    float xn1 = (x1-mu)*rstd*lg.y + lbe.y;
    float2 st;
    st.x = 0.5f*xn0*(1.0f + erff(xn0*0.70710678118654752f));
    st.y = 0.5f*xn1*(1.0f + erff(xn1*0.70710678118654752f));
    *(float2*)(out + base) = st;
  }
}

extern "C" void kernel_launch(void* const* d_in, const int* in_sizes, int n_in,
                              void* d_out, int out_size, void* d_ws, size_t ws_size,
                              hipStream_t stream) {
  const float* h      = (const float*)d_in[0];
  const float* U      = (const float*)d_in[1];
  const float* W      = (const float*)d_in[2];
  const float* lin_w  = (const float*)d_in[3];
  const float* lin_b  = (const float*)d_in[4];
  const float* ln_g   = (const float*)d_in[5];
  const float* ln_b2  = (const float*)d_in[6];
  const int* ei       = (const int*)d_in[7];
  const int* src = ei;
  const int* dst = ei + EN;
  float* out = (float*)d_out;

  char* wp = (char*)d_ws;
  float* hp     = (float*)wp; wp += (size_t)8*BN*MN*CN*sizeof(float);    // 16.8 MB
  u16*   ohatT  = (u16*)wp;   wp += (size_t)BN*CN*MN*sizeof(u16);        // 1.05 MB
  u16*   h16    = (u16*)wp;   wp += (size_t)NN*CN*sizeof(u16);           // 33.5 MB
  u16*   ht16   = (u16*)wp;   wp += (size_t)BN*CN*NPGN*sizeof(u16);      // 33.5 MB
  u16*   U16b   = (u16*)wp;   wp += (size_t)BN*NPGN*MN*sizeof(u16);      // 16.8 MB
  u16*   Ut16   = (u16*)wp;   wp += (size_t)BN*MN*NPGN*sizeof(u16);      // 16.8 MB
  u16*   wsw    = (u16*)wp;   wp += (size_t)CN*CN*sizeof(u16);           // 32 KB
  u16*   WT16   = (u16*)wp;   wp += (size_t)MN*CN*CN*sizeof(u16);        // 2.1 MB
  int*   deg    = (int*)wp;   wp += (size_t)NN*sizeof(int);
  int*   rowst  = (int*)wp;   wp += (size_t)NN*sizeof(int);
  int*   cursor = (int*)wp;   wp += (size_t)NN*sizeof(int);
  int*   csr    = (int*)wp;   wp += (size_t)EN*sizeof(int);              // 4.2 MB
  int*   bsum   = (int*)wp;   wp += 512*sizeof(int);
  int*   bofs   = (int*)wp;   wp += 512*sizeof(int);

  hipMemsetAsync(deg,    0, (size_t)NN*sizeof(int), stream);
  hipMemsetAsync(cursor, 0, (size_t)NN*sizeof(int), stream);

  k_count<<<EN/256, 256, 0, stream>>>(dst, deg);
  k_scan1<<<NN/512, 512, 0, stream>>>(deg, rowst, bsum);
  k_scan2<<<1, 256, 0, stream>>>(bsum, bofs);
  k_scan3<<<NN/256, 256, 0, stream>>>(rowst, bofs);
  k_fill<<<EN/256, 256, 0, stream>>>(src, dst, rowst, cursor, csr);

  k_prepw<<<8, 256, 0, stream>>>(lin_w, wsw);
  k_prepWT<<<MN, 256, 0, stream>>>(W, WT16);
  k_prep_h<<<BN*32, 256, 0, stream>>>(h, h16, ht16);
  k_prep_U<<<BN*16, 256, 0, stream>>>(U, U16b, Ut16);

  k_hhat<<<BN*16, 256, 0, stream>>>(Ut16, ht16, hp);
  k_ohat<<<MN*4, 256, 0, stream>>>(hp, WT16, ohatT);

  k_localep<<<NN/32, 256, 0, stream>>>(h16, U16b, ohatT, wsw, rowst, deg, csr,
                                       lin_b, ln_g, ln_b2, out);
}

// Round 5
// 398.033 us; speedup vs baseline: 1.0883x; 1.0883x over previous
//
#include <hip/hip_runtime.h>
#include <math.h>

#define NN   131072
#define CN   128
#define BN   64
#define NPGN 2048
#define MN   64
#define EN   1048576

typedef unsigned short u16;
typedef unsigned int   u32;
typedef __attribute__((ext_vector_type(8))) short short8;
typedef __attribute__((ext_vector_type(4))) float f32x4;

__device__ __forceinline__ float bf2f(u16 u){ return __uint_as_float(((u32)u)<<16); }
__device__ __forceinline__ u16 f2bf(float f){
  u32 x = __float_as_uint(f);
  return (u16)((x + 0x7fffu + ((x>>16)&1u)) >> 16);
}

// ---------------- graph build ----------------
__global__ void k_count(const int* __restrict__ dst, int* __restrict__ deg){
  int e = blockIdx.x*256 + threadIdx.x;
  atomicAdd(&deg[dst[e]], 1);
}

__global__ void k_scan1(const int* __restrict__ deg, int* __restrict__ rowst, int* __restrict__ bsum){
  __shared__ int s[512];
  const int t = threadIdx.x;
  const int i = blockIdx.x*512 + t;
  int v = deg[i];
  s[t] = v;
  __syncthreads();
  for (int off=1; off<512; off<<=1){
    int a = (t>=off) ? s[t-off] : 0;
    __syncthreads();
    s[t] += a;
    __syncthreads();
  }
  rowst[i] = s[t] - v;
  if (t==511) bsum[blockIdx.x] = s[511];
}

__global__ void k_scan2(const int* __restrict__ bsum, int* __restrict__ bofs){
  __shared__ int s[256];
  const int t = threadIdx.x;
  int v = bsum[t];
  s[t] = v;
  __syncthreads();
  for (int off=1; off<256; off<<=1){
    int a = (t>=off) ? s[t-off] : 0;
    __syncthreads();
    s[t] += a;
    __syncthreads();
  }
  bofs[t] = s[t] - v;
}

__global__ void k_scan3(int* __restrict__ rowst, const int* __restrict__ bofs){
  int i = blockIdx.x*256 + threadIdx.x;
  rowst[i] += bofs[i>>9];
}

__global__ void k_fill(const int* __restrict__ src, const int* __restrict__ dst,
                       const int* __restrict__ rowst, int* __restrict__ cursor,
                       int* __restrict__ csr){
  int e = blockIdx.x*256 + threadIdx.x;
  int d = dst[e];
  int p = atomicAdd(&cursor[d], 1);
  csr[rowst[d] + p] = src[e];
}

// ---------------- weight prep: B-fragment-swizzled bf16 lin_w (round-4 validated) ----------------
__global__ void k_prepw(const float* __restrict__ lin_w, u16* __restrict__ wsw){
  int tid = blockIdx.x*256 + threadIdx.x;   // 2048 total
  int g = tid >> 6, L = tid & 63;
  int ct = g >> 2, ks = g & 3;
  int o = L & 15, q = L >> 4;
  const float* srcp = lin_w + (ct*16+o)*CN + ks*32 + q*8;
  u16 tmp[8];
  #pragma unroll
  for (int j=0;j<8;++j) tmp[j] = f2bf(srcp[j]);
  *(uint4*)(wsw + (size_t)tid*8) = *(const uint4*)tmp;
}

// ---------------- weight prep: W[m][c][o] fp32 -> WT16[m][o][c] bf16 ----------------
__global__ void k_prepWT(const float* __restrict__ W, u16* __restrict__ WT16){
  __shared__ u16 st[128*132];    // 33.8 KB
  const int t = threadIdx.x;
  const int m = blockIdx.x;
  const float* Wm = W + (size_t)m*CN*CN;
  #pragma unroll
  for (int it=0; it<16; ++it){
    int flat = (it*256 + t)*4;
    int c = flat >> 7, o = flat & 127;
    float4 v = *(const float4*)(Wm + flat);
    st[(o+0)*132 + c] = f2bf(v.x);
    st[(o+1)*132 + c] = f2bf(v.y);
    st[(o+2)*132 + c] = f2bf(v.z);
    st[(o+3)*132 + c] = f2bf(v.w);
  }
  __syncthreads();
  u16* dstm = WT16 + (size_t)m*CN*CN;
  #pragma unroll
  for (int it=0; it<8; ++it){
    int oidx = (it*256 + t)*8;
    int o = oidx >> 7, c = oidx & 127;
    uint4 v = *(const uint4*)&st[o*132 + c];
    *(uint4*)(dstm + (size_t)o*CN + c) = v;
  }
}

// ---------------- prep: h fp32 -> h16 natural bf16 + ht16[b][c][n] bf16 ----------------
// grid 64*32, 256 thr; tile = 64 n-rows x 128 c
__global__ void k_prep_h(const float* __restrict__ h, u16* __restrict__ h16, u16* __restrict__ ht16){
  __shared__ u16 st[CN*72];   // st[c*72 + r], r<64
  const int t = threadIdx.x;
  const int b = blockIdx.x >> 5;
  const int n0 = (blockIdx.x & 31)*64;
  const float* srcb = h + ((size_t)b*NPGN + n0)*CN;
  u16* natb = h16 + ((size_t)b*NPGN + n0)*CN;
  #pragma unroll
  for (int j=0;j<8;++j){
    int fidx = (j*256+t)*4;
    int r = fidx>>7, c = fidx&127;
    float4 v = *(const float4*)(srcb + fidx);
    u16 q0=f2bf(v.x), q1=f2bf(v.y), q2=f2bf(v.z), q3=f2bf(v.w);
    ushort4 nv; nv.x=q0; nv.y=q1; nv.z=q2; nv.w=q3;
    *(ushort4*)(natb + fidx) = nv;
    st[(c+0)*72 + r] = q0; st[(c+1)*72 + r] = q1;
    st[(c+2)*72 + r] = q2; st[(c+3)*72 + r] = q3;
  }
  __syncthreads();
  #pragma unroll
  for (int j=0;j<4;++j){
    int oidx = (j*256+t)*8;
    int c = oidx>>6, nn = oidx&63;
    uint4 v = *(const uint4*)&st[c*72 + nn];
    *(uint4*)(ht16 + ((size_t)b*CN + c)*NPGN + n0 + nn) = v;
  }
}

// ---------------- prep: U fp32 -> U16 natural bf16 + Ut16[b][m][n] bf16 ----------------
// grid 64*16, 256 thr; tile = 128 n-rows x 64 m
__global__ void k_prep_U(const float* __restrict__ U, u16* __restrict__ U16, u16* __restrict__ Ut16){
  __shared__ u16 st2[MN*136];   // st2[m*136 + r], r<128
  const int t = threadIdx.x;
  const int b = blockIdx.x >> 4;
  const int n0 = (blockIdx.x & 15)*128;
  const float* srcb = U + ((size_t)b*NPGN + n0)*MN;
  u16* natb = U16 + ((size_t)b*NPGN + n0)*MN;
  #pragma unroll
  for (int j=0;j<8;++j){
    int fidx = (j*256+t)*4;
    int r = fidx>>6, mm = fidx&63;
    float4 v = *(const float4*)(srcb + fidx);
    u16 q0=f2bf(v.x), q1=f2bf(v.y), q2=f2bf(v.z), q3=f2bf(v.w);
    ushort4 nv; nv.x=q0; nv.y=q1; nv.z=q2; nv.w=q3;
    *(ushort4*)(natb + fidx) = nv;
    st2[(mm+0)*136 + r] = q0; st2[(mm+1)*136 + r] = q1;
    st2[(mm+2)*136 + r] = q2; st2[(mm+3)*136 + r] = q3;
  }
  __syncthreads();
  #pragma unroll
  for (int j=0;j<4;++j){
    int oidx = (j*256+t)*8;
    int mm = oidx>>7, nn = oidx&127;
    uint4 v = *(const uint4*)&st2[mm*136 + nn];
    *(uint4*)(Ut16 + ((size_t)b*MN + mm)*NPGN + n0 + nn) = v;
  }
}

// ---------------- h_hat partials (MFMA): hp[q][b][m][c], K-chunk 256, c-half per block ----------------
// C[m][c] = sum_n Ut16[b][m][n] * ht16[b][c][n]; grid 64*8*2, 4 waves, wave = m-tile
__global__ __launch_bounds__(256) void k_hhat(const u16* __restrict__ Ut16,
                                              const u16* __restrict__ ht16,
                                              float* __restrict__ hp){
  const int t = threadIdx.x;
  const int L = t & 63, w = t >> 6;
  const int b  = blockIdx.x >> 4;
  const int q  = (blockIdx.x >> 1) & 7;
  const int ch = blockIdx.x & 1;            // c-half
  const int lo = L & 15, qd = (L >> 4) << 3;
  f32x4 acc[4] = {};
  const u16* Arow  = Ut16 + ((size_t)(b*MN + w*16 + lo))*NPGN + q*256 + qd;
  const u16* Bbase = ht16 + ((size_t)(b*CN + ch*64 + lo))*NPGN + q*256 + qd;
  #pragma unroll
  for (int ks=0; ks<8; ++ks){
    short8 af = *(const short8*)(Arow + ks*32);
    #pragma unroll
    for (int ct=0; ct<4; ++ct){
      short8 bf = *(const short8*)(Bbase + (size_t)ct*16*NPGN + ks*32);
      acc[ct] = __builtin_amdgcn_mfma_f32_16x16x32_bf16(af, bf, acc[ct], 0, 0, 0);
    }
  }
  const int rb = w*16 + ((L>>4)<<2);
  float* dstb = hp + ((size_t)q*BN + b)*MN*CN;
  #pragma unroll
  for (int ct=0; ct<4; ++ct)
    #pragma unroll
    for (int r=0; r<4; ++r)
      dstb[(size_t)(rb+r)*CN + ch*64 + ct*16 + lo] = acc[ct][r];
}

// ---------------- out_hat (MFMA): ohatT[b][o][m] = bf16( sum_c hh[b,c]*W[m,c,o] ) ----------------
// grid 64m*4bq, 256 thr (4 waves). hh = sum_q hp, hi/lo bf16 split for fp32 fidelity.
__global__ __launch_bounds__(256) void k_ohat(const float* __restrict__ hp,
                                              const u16* __restrict__ WT16,
                                              u16* __restrict__ ohatT){
  __shared__ u16 shHi[16*132];   // 4.2 KB
  __shared__ u16 shLo[16*132];   // 4.2 KB
  const int t = threadIdx.x;
  const int m  = blockIdx.x >> 2;
  const int bq = blockIdx.x & 3;       // b-quarter: rows bq*16 .. bq*16+15

  // Stage 1: hh[bl][c] = sum_q hp[q][bq*16+bl][m][c]; split into hi/lo bf16
  {
    const int bl = t >> 4;             // 0..15
    const int c0 = (t & 15) * 8;       // 8 channels
    const size_t S = (size_t)BN*MN*CN;
    const float* base = hp + ((size_t)(bq*16 + bl)*MN + m)*CN + c0;
    float a[8] = {0,0,0,0,0,0,0,0};
    #pragma unroll
    for (int q=0; q<8; ++q){
      float4 v0 = *(const float4*)(base + q*S);
      float4 v1 = *(const float4*)(base + q*S + 4);
      a[0]+=v0.x; a[1]+=v0.y; a[2]+=v0.z; a[3]+=v0.w;
      a[4]+=v1.x; a[5]+=v1.y; a[6]+=v1.z; a[7]+=v1.w;
    }
    u16 hi[8], lo[8];
    #pragma unroll
    for (int j=0;j<8;++j){
      hi[j] = f2bf(a[j]);
      lo[j] = f2bf(a[j] - bf2f(hi[j]));
    }
    *(uint4*)&shHi[bl*132 + c0] = *(const uint4*)hi;
    *(uint4*)&shLo[bl*132 + c0] = *(const uint4*)lo;
  }
  __syncthreads();

  // Stage 2: wave w -> o-range w*32..w*32+31 (2 o-tiles), K=128 (4 ks), hi+lo MFMA
  const int L = t & 63, w = t >> 6;
  const int lo16 = L & 15, qd = (L >> 4) << 3;
  const u16* WTm = WT16 + (size_t)m*CN*CN;
  f32x4 acc[2] = {};
  #pragma unroll
  for (int ks=0; ks<4; ++ks){
    short8 ah = *(const short8*)&shHi[lo16*132 + ks*32 + qd];
    short8 al = *(const short8*)&shLo[lo16*132 + ks*32 + qd];
    #pragma unroll
    for (int ot=0; ot<2; ++ot){
      short8 bf = *(const short8*)(WTm + (size_t)(w*32 + ot*16 + lo16)*CN + ks*32 + qd);
      acc[ot] = __builtin_amdgcn_mfma_f32_16x16x32_bf16(ah, bf, acc[ot], 0, 0, 0);
      acc[ot] = __builtin_amdgcn_mfma_f32_16x16x32_bf16(al, bf, acc[ot], 0, 0, 0);
    }
  }
  const int rb = (L>>4)<<2;
  #pragma unroll
  for (int ot=0; ot<2; ++ot){
    #pragma unroll
    for (int r=0; r<4; ++r){
      int b = bq*16 + rb + r;
      int o = w*32 + ot*16 + lo16;
      ohatT[((size_t)b*CN + o)*MN + m] = f2bf(acc[ot][r]);
    }
  }
}

// ---------------- fused: gather-mean + (local+spec) MFMA + LN + GELU ----------------
__device__ __forceinline__ void unp_add(float* a, uint4 p){
  a[0]+=bf2f((u16)(p.x&0xffffu)); a[1]+=bf2f((u16)(p.x>>16));
  a[2]+=bf2f((u16)(p.y&0xffffu)); a[3]+=bf2f((u16)(p.y>>16));
  a[4]+=bf2f((u16)(p.z&0xffffu)); a[5]+=bf2f((u16)(p.z>>16));
  a[6]+=bf2f((u16)(p.w&0xffffu)); a[7]+=bf2f((u16)(p.w>>16));
}

__global__ __launch_bounds__(256,6) void k_localep(
    const u16* __restrict__ h16, const u16* __restrict__ U16,
    const u16* __restrict__ ohatT, const u16* __restrict__ wsw,
    const int* __restrict__ rowst, const int* __restrict__ deg, const int* __restrict__ csr,
    const float* __restrict__ lin_b, const float* __restrict__ ln_g,
    const float* __restrict__ ln_beta, float* __restrict__ out){
  __shared__ u16 sv[32*136];     // 8.7 KB  mean-neighbor rows (bf16, pitch 136)
  __shared__ u16 sx16[32*132];   // 8.4 KB  local+spec result (bf16)
  const int t = threadIdx.x;
  const int w = t>>6, lane = t&63;
  const size_t n0 = (size_t)blockIdx.x*32;

  // Phase A v4: lane owns 8 channels (16B), 4 edge-slots; per node-pair one
  // straight-line 16-edge round (8 independent uint4 loads in flight); rare tail.
  {
    const int g   = lane >> 4;    // edge slot 0..3
    const int c16 = lane & 15;    // channel group: channels c16*8 .. c16*8+7
    const u16* hcol = h16 + c16*8;
    #pragma unroll
    for (int p=0; p<4; ++p){
      const int iA = p*8 + w;
      const int iB = p*8 + 4 + w;
      const int nA = (int)n0 + iA, nB = (int)n0 + iB;
      const int rsA = rowst[nA], dgA = deg[nA];
      const int rsB = rowst[nB], dgB = deg[nB];
      const int reA = rsA + dgA, reB = rsB + dgB;
      float accA[8] = {0.f,0.f,0.f,0.f,0.f,0.f,0.f,0.f};
      float accB[8] = {0.f,0.f,0.f,0.f,0.f,0.f,0.f,0.f};
      int eA = rsA + g, eB = rsB + g;
      // round 1: covers edges rs..rs+15 of both nodes (99.6% of Poisson(8) nodes)
      {
        const bool a0 = eA    < reA, a1 = eA+4  < reA, a2 = eA+8  < reA, a3 = eA+12 < reA;
        const bool b0 = eB    < reB, b1 = eB+4  < reB, b2 = eB+8  < reB, b3 = eB+12 < reB;
        int sa0 = a0 ? csr[eA]    : 0, sa1 = a1 ? csr[eA+4]  : 0;
        int sa2 = a2 ? csr[eA+8]  : 0, sa3 = a3 ? csr[eA+12] : 0;
        int sb0 = b0 ? csr[eB]    : 0, sb1 = b1 ? csr[eB+4]  : 0;
        int sb2 = b2 ? csr[eB+8]  : 0, sb3 = b3 ? csr[eB+12] : 0;
        uint4 qa0={0u,0u,0u,0u}, qa1={0u,0u,0u,0u}, qa2={0u,0u,0u,0u}, qa3={0u,0u,0u,0u};
        uint4 qb0={0u,0u,0u,0u}, qb1={0u,0u,0u,0u}, qb2={0u,0u,0u,0u}, qb3={0u,0u,0u,0u};
        if (a0) qa0 = *(const uint4*)(hcol + (size_t)sa0*CN);
        if (a1) qa1 = *(const uint4*)(hcol + (size_t)sa1*CN);
        if (a2) qa2 = *(const uint4*)(hcol + (size_t)sa2*CN);
        if (a3) qa3 = *(const uint4*)(hcol + (size_t)sa3*CN);
        if (b0) qb0 = *(const uint4*)(hcol + (size_t)sb0*CN);
        if (b1) qb1 = *(const uint4*)(hcol + (size_t)sb1*CN);
        if (b2) qb2 = *(const uint4*)(hcol + (size_t)sb2*CN);
        if (b3) qb3 = *(const uint4*)(hcol + (size_t)sb3*CN);
        unp_add(accA, qa0); unp_add(accA, qa1); unp_add(accA, qa2); unp_add(accA, qa3);
        unp_add(accB, qb0); unp_add(accB, qb1); unp_add(accB, qb2); unp_add(accB, qb3);
        eA += 16; eB += 16;
      }
      // rare tail: deg > 16 (P ~ 0.4%)
      while (eA < reA || eB < reB){
        const bool a0 = eA < reA, a1 = eA+4 < reA;
        const bool b0 = eB < reB, b1 = eB+4 < reB;
        int sa0 = a0 ? csr[eA]   : 0, sa1 = a1 ? csr[eA+4] : 0;
        int sb0 = b0 ? csr[eB]   : 0, sb1 = b1 ? csr[eB+4] : 0;
        uint4 qa0={0u,0u,0u,0u}, qa1={0u,0u,0u,0u}, qb0={0u,0u,0u,0u}, qb1={0u,0u,0u,0u};
        if (a0) qa0 = *(const uint4*)(hcol + (size_t)sa0*CN);
        if (a1) qa1 = *(const uint4*)(hcol + (size_t)sa1*CN);
        if (b0) qb0 = *(const uint4*)(hcol + (size_t)sb0*CN);
        if (b1) qb1 = *(const uint4*)(hcol + (size_t)sb1*CN);
        unp_add(accA, qa0); unp_add(accA, qa1);
        unp_add(accB, qb0); unp_add(accB, qb1);
        eA += 8; eB += 8;
      }
      // fold the 4 edge-slots: lanes {c16, c16+16, c16+32, c16+48} -> all
      #pragma unroll
      for (int j=0;j<8;++j){
        accA[j] += __shfl_xor(accA[j],16); accA[j] += __shfl_xor(accA[j],32);
        accB[j] += __shfl_xor(accB[j],16); accB[j] += __shfl_xor(accB[j],32);
      }
      const float invA = 1.0f / fmaxf((float)dgA, 1.0f);
      const float invB = 1.0f / fmaxf((float)dgB, 1.0f);
      if (g==0){
        u16 ta[8], tb[8];
        #pragma unroll
        for (int j=0;j<8;++j){ ta[j]=f2bf(accA[j]*invA); tb[j]=f2bf(accB[j]*invB); }
        *(uint4*)&sv[iA*136 + c16*8] = *(const uint4*)ta;
        *(uint4*)&sv[iB*136 + c16*8] = *(const uint4*)tb;
      }
    }
  }
  __syncthreads();

  // Phase B: acc = local (sv @ lin_w^T, K=128) + spec (U16 @ ohatT^T, K=64)
  // Both produce the same 32x128 output tile with identical C/D mapping.
  const int rt = w&1, cb = w>>1;
  const int lo16 = lane & 15, qd = (lane>>4)<<3;
  f32x4 acc[4] = {};
  #pragma unroll
  for (int ks=0; ks<4; ++ks){
    short8 af = *(const short8*)&sv[(rt*16 + lo16)*136 + ks*32 + qd];
    #pragma unroll
    for (int c4=0; c4<4; ++c4){
      const short8 bf = *(const short8*)(wsw + ((size_t)((cb*4+c4)*4+ks)*64 + lane)*8);
      acc[c4] = __builtin_amdgcn_mfma_f32_16x16x32_bf16(af, bf, acc[c4], 0, 0, 0);
    }
  }
  {
    const int b = (int)(n0 >> 11);                              // node block -> batch
    const u16* Au = U16  + ((size_t)(n0 + rt*16 + lo16))*MN + qd;
    const u16* Bu = ohatT + ((size_t)(b*CN + cb*64 + lo16))*MN + qd;
    #pragma unroll
    for (int ks=0; ks<2; ++ks){
      short8 af = *(const short8*)(Au + ks*32);
      #pragma unroll
      for (int c4=0; c4<4; ++c4){
        short8 bf = *(const short8*)(Bu + (size_t)c4*16*MN + ks*32);
        acc[c4] = __builtin_amdgcn_mfma_f32_16x16x32_bf16(af, bf, acc[c4], 0, 0, 0);
      }
    }
  }
  #pragma unroll
  for (int c4=0; c4<4; ++c4){
    int col = cb*64 + c4*16 + lo16;
    int rb = rt*16 + ((lane>>4)<<2);
    #pragma unroll
    for (int r=0; r<4; ++r) sx16[(rb+r)*132 + col] = f2bf(acc[c4][r]);
  }
  __syncthreads();

  // Phase C: x = h + (spec+local) + bias; LayerNorm; exact GELU
  float2 lb    = *(const float2*)(lin_b  + 2*lane);
  float2 lg    = *(const float2*)(ln_g   + 2*lane);
  float2 lbe   = *(const float2*)(ln_beta+ 2*lane);
  for (int r=0; r<8; ++r){
    int i = r*4 + w;
    size_t base = (n0 + i)*CN + 2*lane;
    u32 hA = *(const u32*)(h16 + base);
    u32 lA = *(const u32*)&sx16[i*132 + 2*lane];
    float x0 = bf2f((u16)(hA&0xffffu)) + bf2f((u16)(lA&0xffffu)) + lb.x;
    float x1 = bf2f((u16)(hA>>16))     + bf2f((u16)(lA>>16))     + lb.y;
    float s  = x0 + x1;
    float ss = fmaf(x0,x0, x1*x1);
    #pragma unroll
    for (int d=1; d<64; d<<=1){ s += __shfl_xor(s,d); ss += __shfl_xor(ss,d); }
    float mu  = s*(1.0f/128.0f);
    float var = ss*(1.0f/128.0f) - mu*mu;
    float rstd = rsqrtf(var + 1e-5f);
    float xn0 = (x0-mu)*rstd*lg.x + lbe.x;
    float xn1 = (x1-mu)*rstd*lg.y + lbe.y;
    float2 st;
    st.x = 0.5f*xn0*(1.0f + erff(xn0*0.70710678118654752f));
    st.y = 0.5f*xn1*(1.0f + erff(xn1*0.70710678118654752f));
    *(float2*)(out + base) = st;
  }
}

extern "C" void kernel_launch(void* const* d_in, const int* in_sizes, int n_in,
                              void* d_out, int out_size, void* d_ws, size_t ws_size,
                              hipStream_t stream) {
  const float* h      = (const float*)d_in[0];
  const float* U      = (const float*)d_in[1];
  const float* W      = (const float*)d_in[2];
  const float* lin_w  = (const float*)d_in[3];
  const float* lin_b  = (const float*)d_in[4];
  const float* ln_g   = (const float*)d_in[5];
  const float* ln_b2  = (const float*)d_in[6];
  const int* ei       = (const int*)d_in[7];
  const int* src = ei;
  const int* dst = ei + EN;
  float* out = (float*)d_out;

  char* wp = (char*)d_ws;
  float* hp     = (float*)wp; wp += (size_t)8*BN*MN*CN*sizeof(float);    // 16.8 MB
  u16*   ohatT  = (u16*)wp;   wp += (size_t)BN*CN*MN*sizeof(u16);        // 1.05 MB
  u16*   h16    = (u16*)wp;   wp += (size_t)NN*CN*sizeof(u16);           // 33.5 MB
  u16*   ht16   = (u16*)wp;   wp += (size_t)BN*CN*NPGN*sizeof(u16);      // 33.5 MB
  u16*   U16b   = (u16*)wp;   wp += (size_t)BN*NPGN*MN*sizeof(u16);      // 16.8 MB
  u16*   Ut16   = (u16*)wp;   wp += (size_t)BN*MN*NPGN*sizeof(u16);      // 16.8 MB
  u16*   wsw    = (u16*)wp;   wp += (size_t)CN*CN*sizeof(u16);           // 32 KB
  u16*   WT16   = (u16*)wp;   wp += (size_t)MN*CN*CN*sizeof(u16);        // 2.1 MB
  int*   deg    = (int*)wp;   wp += (size_t)NN*sizeof(int);
  int*   rowst  = (int*)wp;   wp += (size_t)NN*sizeof(int);
  int*   cursor = (int*)wp;   wp += (size_t)NN*sizeof(int);
  int*   csr    = (int*)wp;   wp += (size_t)EN*sizeof(int);              // 4.2 MB
  int*   bsum   = (int*)wp;   wp += 512*sizeof(int);
  int*   bofs   = (int*)wp;   wp += 512*sizeof(int);

  hipMemsetAsync(deg,    0, (size_t)NN*sizeof(int), stream);
  hipMemsetAsync(cursor, 0, (size_t)NN*sizeof(int), stream);

  k_count<<<EN/256, 256, 0, stream>>>(dst, deg);
  k_scan1<<<NN/512, 512, 0, stream>>>(deg, rowst, bsum);
  k_scan2<<<1, 256, 0, stream>>>(bsum, bofs);
  k_scan3<<<NN/256, 256, 0, stream>>>(rowst, bofs);
  k_fill<<<EN/256, 256, 0, stream>>>(src, dst, rowst, cursor, csr);

  k_prepw<<<8, 256, 0, stream>>>(lin_w, wsw);
  k_prepWT<<<MN, 256, 0, stream>>>(W, WT16);
  k_prep_h<<<BN*32, 256, 0, stream>>>(h, h16, ht16);
  k_prep_U<<<BN*16, 256, 0, stream>>>(U, U16b, Ut16);

  k_hhat<<<BN*16, 256, 0, stream>>>(Ut16, ht16, hp);
  k_ohat<<<MN*4, 256, 0, stream>>>(hp, WT16, ohatT);

  k_localep<<<NN/32, 256, 0, stream>>>(h16, U16b, ohatT, wsw, rowst, deg, csr,
                                       lin_b, ln_g, ln_b2, out);
}

// Round 6
// 383.534 us; speedup vs baseline: 1.1294x; 1.0378x over previous
//
#include <hip/hip_runtime.h>
#include <math.h>

#define NN   131072
#define CN   128
#define BN   64
#define NPGN 2048
#define MN   64
#define EN   1048576

typedef unsigned short u16;
typedef unsigned int   u32;
typedef __attribute__((ext_vector_type(8))) short short8;
typedef __attribute__((ext_vector_type(4))) float f32x4;

__device__ __forceinline__ float bf2f(u16 u){ return __uint_as_float(((u32)u)<<16); }
__device__ __forceinline__ u16 f2bf(float f){
  u32 x = __float_as_uint(f);
  return (u16)((x + 0x7fffu + ((x>>16)&1u)) >> 16);
}

// ---------------- graph build ----------------
__global__ void k_count(const int* __restrict__ dst, int* __restrict__ deg){
  int e = blockIdx.x*256 + threadIdx.x;
  atomicAdd(&deg[dst[e]], 1);
}

__global__ void k_scan1(const int* __restrict__ deg, int* __restrict__ rowst, int* __restrict__ bsum){
  __shared__ int s[512];
  const int t = threadIdx.x;
  const int i = blockIdx.x*512 + t;
  int v = deg[i];
  s[t] = v;
  __syncthreads();
  for (int off=1; off<512; off<<=1){
    int a = (t>=off) ? s[t-off] : 0;
    __syncthreads();
    s[t] += a;
    __syncthreads();
  }
  rowst[i] = s[t] - v;
  if (t==511) bsum[blockIdx.x] = s[511];
}

__global__ void k_scan2(const int* __restrict__ bsum, int* __restrict__ bofs){
  __shared__ int s[256];
  const int t = threadIdx.x;
  int v = bsum[t];
  s[t] = v;
  __syncthreads();
  for (int off=1; off<256; off<<=1){
    int a = (t>=off) ? s[t-off] : 0;
    __syncthreads();
    s[t] += a;
    __syncthreads();
  }
  bofs[t] = s[t] - v;
}

__global__ void k_scan3(int* __restrict__ rowst, const int* __restrict__ bofs){
  int i = blockIdx.x*256 + threadIdx.x;
  rowst[i] += bofs[i>>9];
}

__global__ void k_fill(const int* __restrict__ src, const int* __restrict__ dst,
                       const int* __restrict__ rowst, int* __restrict__ cursor,
                       int* __restrict__ csr){
  int e = blockIdx.x*256 + threadIdx.x;
  int d = dst[e];
  int p = atomicAdd(&cursor[d], 1);
  csr[rowst[d] + p] = src[e];
}

// ---------------- fused prep: h, U, lin_w (range-switched; LDS union 18.4 KB) ----------------
__global__ __launch_bounds__(256) void k_prep_all(
    const float* __restrict__ h, u16* __restrict__ h16, u16* __restrict__ ht16,
    const float* __restrict__ U, u16* __restrict__ U16, u16* __restrict__ Ut16,
    const float* __restrict__ lin_w, u16* __restrict__ wsw){
  __shared__ u16 stu[CN*72];   // 18.4 KB (union; prep_U needs 17.4 KB)
  const int t = threadIdx.x;
  const int bid = blockIdx.x;

  if (bid < 2048){
    // ---- prep_h: tile = 64 n-rows x 128 c ----
    const int b = bid >> 5;
    const int n0 = (bid & 31)*64;
    const float* srcb = h + ((size_t)b*NPGN + n0)*CN;
    u16* natb = h16 + ((size_t)b*NPGN + n0)*CN;
    #pragma unroll
    for (int j=0;j<8;++j){
      int fidx = (j*256+t)*4;
      int r = fidx>>7, c = fidx&127;
      float4 v = *(const float4*)(srcb + fidx);
      u16 q0=f2bf(v.x), q1=f2bf(v.y), q2=f2bf(v.z), q3=f2bf(v.w);
      ushort4 nv; nv.x=q0; nv.y=q1; nv.z=q2; nv.w=q3;
      *(ushort4*)(natb + fidx) = nv;
      stu[(c+0)*72 + r] = q0; stu[(c+1)*72 + r] = q1;
      stu[(c+2)*72 + r] = q2; stu[(c+3)*72 + r] = q3;
    }
    __syncthreads();
    #pragma unroll
    for (int j=0;j<4;++j){
      int oidx = (j*256+t)*8;
      int c = oidx>>6, nn = oidx&63;
      uint4 v = *(const uint4*)&stu[c*72 + nn];
      *(uint4*)(ht16 + ((size_t)b*CN + c)*NPGN + n0 + nn) = v;
    }
  } else if (bid < 3072){
    // ---- prep_U: tile = 128 n-rows x 64 m ----
    const int ub = bid - 2048;
    const int b = ub >> 4;
    const int n0 = (ub & 15)*128;
    const float* srcb = U + ((size_t)b*NPGN + n0)*MN;
    u16* natb = U16 + ((size_t)b*NPGN + n0)*MN;
    #pragma unroll
    for (int j=0;j<8;++j){
      int fidx = (j*256+t)*4;
      int r = fidx>>6, mm = fidx&63;
      float4 v = *(const float4*)(srcb + fidx);
      u16 q0=f2bf(v.x), q1=f2bf(v.y), q2=f2bf(v.z), q3=f2bf(v.w);
      ushort4 nv; nv.x=q0; nv.y=q1; nv.z=q2; nv.w=q3;
      *(ushort4*)(natb + fidx) = nv;
      stu[(mm+0)*136 + r] = q0; stu[(mm+1)*136 + r] = q1;
      stu[(mm+2)*136 + r] = q2; stu[(mm+3)*136 + r] = q3;
    }
    __syncthreads();
    #pragma unroll
    for (int j=0;j<4;++j){
      int oidx = (j*256+t)*8;
      int mm = oidx>>7, nn = oidx&127;
      uint4 v = *(const uint4*)&stu[mm*136 + nn];
      *(uint4*)(Ut16 + ((size_t)b*MN + mm)*NPGN + n0 + nn) = v;
    }
  } else {
    // ---- prepw: B-fragment-swizzled bf16 lin_w ----
    int tid = (bid - 3072)*256 + t;   // 2048 total
    int g = tid >> 6, L = tid & 63;
    int ct = g >> 2, ks = g & 3;
    int o = L & 15, q = L >> 4;
    const float* srcp = lin_w + (ct*16+o)*CN + ks*32 + q*8;
    u16 tmp[8];
    #pragma unroll
    for (int j=0;j<8;++j) tmp[j] = f2bf(srcp[j]);
    *(uint4*)(wsw + (size_t)tid*8) = *(const uint4*)tmp;
  }
}

// ---------------- weight prep: W[m][c][o] fp32 -> WT16[m][o][c] bf16 ----------------
__global__ void k_prepWT(const float* __restrict__ W, u16* __restrict__ WT16){
  __shared__ u16 st[128*132];    // 33.8 KB
  const int t = threadIdx.x;
  const int m = blockIdx.x;
  const float* Wm = W + (size_t)m*CN*CN;
  #pragma unroll
  for (int it=0; it<16; ++it){
    int flat = (it*256 + t)*4;
    int c = flat >> 7, o = flat & 127;
    float4 v = *(const float4*)(Wm + flat);
    st[(o+0)*132 + c] = f2bf(v.x);
    st[(o+1)*132 + c] = f2bf(v.y);
    st[(o+2)*132 + c] = f2bf(v.z);
    st[(o+3)*132 + c] = f2bf(v.w);
  }
  __syncthreads();
  u16* dstm = WT16 + (size_t)m*CN*CN;
  #pragma unroll
  for (int it=0; it<8; ++it){
    int oidx = (it*256 + t)*8;
    int o = oidx >> 7, c = oidx & 127;
    uint4 v = *(const uint4*)&st[o*132 + c];
    *(uint4*)(dstm + (size_t)o*CN + c) = v;
  }
}

// ---------------- h_hat partials (MFMA): hp[q][b][m][c], K-chunk 256, c-half per block ----------------
// C[m][c] = sum_n Ut16[b][m][n] * ht16[b][c][n]; grid 64*8*2, 4 waves, wave = m-tile
__global__ __launch_bounds__(256) void k_hhat(const u16* __restrict__ Ut16,
                                              const u16* __restrict__ ht16,
                                              float* __restrict__ hp){
  const int t = threadIdx.x;
  const int L = t & 63, w = t >> 6;
  const int b  = blockIdx.x >> 4;
  const int q  = (blockIdx.x >> 1) & 7;
  const int ch = blockIdx.x & 1;            // c-half
  const int lo = L & 15, qd = (L >> 4) << 3;
  f32x4 acc[4] = {};
  const u16* Arow  = Ut16 + ((size_t)(b*MN + w*16 + lo))*NPGN + q*256 + qd;
  const u16* Bbase = ht16 + ((size_t)(b*CN + ch*64 + lo))*NPGN + q*256 + qd;
  #pragma unroll
  for (int ks=0; ks<8; ++ks){
    short8 af = *(const short8*)(Arow + ks*32);
    #pragma unroll
    for (int ct=0; ct<4; ++ct){
      short8 bf = *(const short8*)(Bbase + (size_t)ct*16*NPGN + ks*32);
      acc[ct] = __builtin_amdgcn_mfma_f32_16x16x32_bf16(af, bf, acc[ct], 0, 0, 0);
    }
  }
  const int rb = w*16 + ((L>>4)<<2);
  float* dstb = hp + ((size_t)q*BN + b)*MN*CN;
  #pragma unroll
  for (int ct=0; ct<4; ++ct)
    #pragma unroll
    for (int r=0; r<4; ++r)
      dstb[(size_t)(rb+r)*CN + ch*64 + ct*16 + lo] = acc[ct][r];
}

// ---------------- out_hat (MFMA): ohatT[b][o][m] = bf16( sum_c hh[b,c]*W[m,c,o] ) ----------------
// grid 64m*4bq, 256 thr (4 waves). hh = sum_q hp, hi/lo bf16 split for fp32 fidelity.
__global__ __launch_bounds__(256) void k_ohat(const float* __restrict__ hp,
                                              const u16* __restrict__ WT16,
                                              u16* __restrict__ ohatT){
  __shared__ u16 shHi[16*132];   // 4.2 KB
  __shared__ u16 shLo[16*132];   // 4.2 KB
  const int t = threadIdx.x;
  const int m  = blockIdx.x >> 2;
  const int bq = blockIdx.x & 3;       // b-quarter: rows bq*16 .. bq*16+15

  // Stage 1: hh[bl][c] = sum_q hp[q][bq*16+bl][m][c]; split into hi/lo bf16
  {
    const int bl = t >> 4;             // 0..15
    const int c0 = (t & 15) * 8;       // 8 channels
    const size_t S = (size_t)BN*MN*CN;
    const float* base = hp + ((size_t)(bq*16 + bl)*MN + m)*CN + c0;
    float a[8] = {0,0,0,0,0,0,0,0};
    #pragma unroll
    for (int q=0; q<8; ++q){
      float4 v0 = *(const float4*)(base + q*S);
      float4 v1 = *(const float4*)(base + q*S + 4);
      a[0]+=v0.x; a[1]+=v0.y; a[2]+=v0.z; a[3]+=v0.w;
      a[4]+=v1.x; a[5]+=v1.y; a[6]+=v1.z; a[7]+=v1.w;
    }
    u16 hi[8], lo[8];
    #pragma unroll
    for (int j=0;j<8;++j){
      hi[j] = f2bf(a[j]);
      lo[j] = f2bf(a[j] - bf2f(hi[j]));
    }
    *(uint4*)&shHi[bl*132 + c0] = *(const uint4*)hi;
    *(uint4*)&shLo[bl*132 + c0] = *(const uint4*)lo;
  }
  __syncthreads();

  // Stage 2: wave w -> o-range w*32..w*32+31 (2 o-tiles), K=128 (4 ks), hi+lo MFMA
  const int L = t & 63, w = t >> 6;
  const int lo16 = L & 15, qd = (L >> 4) << 3;
  const u16* WTm = WT16 + (size_t)m*CN*CN;
  f32x4 acc[2] = {};
  #pragma unroll
  for (int ks=0; ks<4; ++ks){
    short8 ah = *(const short8*)&shHi[lo16*132 + ks*32 + qd];
    short8 al = *(const short8*)&shLo[lo16*132 + ks*32 + qd];
    #pragma unroll
    for (int ot=0; ot<2; ++ot){
      short8 bf = *(const short8*)(WTm + (size_t)(w*32 + ot*16 + lo16)*CN + ks*32 + qd);
      acc[ot] = __builtin_amdgcn_mfma_f32_16x16x32_bf16(ah, bf, acc[ot], 0, 0, 0);
      acc[ot] = __builtin_amdgcn_mfma_f32_16x16x32_bf16(al, bf, acc[ot], 0, 0, 0);
    }
  }
  const int rb = (L>>4)<<2;
  #pragma unroll
  for (int ot=0; ot<2; ++ot){
    #pragma unroll
    for (int r=0; r<4; ++r){
      int b = bq*16 + rb + r;
      int o = w*32 + ot*16 + lo16;
      ohatT[((size_t)b*CN + o)*MN + m] = f2bf(acc[ot][r]);
    }
  }
}

// ---------------- fused: gather-mean + (local+spec) MFMA + LN + GELU ----------------
__device__ __forceinline__ void unp_fma(float* a, uint4 p, float m){
  a[0]=fmaf(m, bf2f((u16)(p.x&0xffffu)), a[0]); a[1]=fmaf(m, bf2f((u16)(p.x>>16)), a[1]);
  a[2]=fmaf(m, bf2f((u16)(p.y&0xffffu)), a[2]); a[3]=fmaf(m, bf2f((u16)(p.y>>16)), a[3]);
  a[4]=fmaf(m, bf2f((u16)(p.z&0xffffu)), a[4]); a[5]=fmaf(m, bf2f((u16)(p.z>>16)), a[5]);
  a[6]=fmaf(m, bf2f((u16)(p.w&0xffffu)), a[6]); a[7]=fmaf(m, bf2f((u16)(p.w>>16)), a[7]);
}
__device__ __forceinline__ void unp_add(float* a, uint4 p){
  a[0]+=bf2f((u16)(p.x&0xffffu)); a[1]+=bf2f((u16)(p.x>>16));
  a[2]+=bf2f((u16)(p.y&0xffffu)); a[3]+=bf2f((u16)(p.y>>16));
  a[4]+=bf2f((u16)(p.z&0xffffu)); a[5]+=bf2f((u16)(p.z>>16));
  a[6]+=bf2f((u16)(p.w&0xffffu)); a[7]+=bf2f((u16)(p.w>>16));
}

__global__ __launch_bounds__(256,6) void k_localep(
    const u16* __restrict__ h16, const u16* __restrict__ U16,
    const u16* __restrict__ ohatT, const u16* __restrict__ wsw,
    const int* __restrict__ rowst, const int* __restrict__ deg, const int* __restrict__ csr,
    const float* __restrict__ lin_b, const float* __restrict__ ln_g,
    const float* __restrict__ ln_beta, float* __restrict__ out){
  __shared__ u16 sv[32*136];     // 8.7 KB  mean-neighbor rows (bf16, pitch 136)
  __shared__ u16 sx16[32*132];   // 8.4 KB  local+spec result (bf16)
  const int t = threadIdx.x;
  const int w = t>>6, lane = t&63;
  const size_t n0 = (size_t)blockIdx.x*32;

  // Phase A v5: branchless round-1. Lane owns 8 channels (16B), 4 edge-slots.
  // All 8 csr loads + all 8 row loads issue unconditionally (clamped addresses,
  // fma-masked accumulate) => no exec-mask branches fencing the scheduler.
  {
    const int g   = lane >> 4;    // edge slot 0..3
    const int c16 = lane & 15;    // channel group: channels c16*8 .. c16*8+7
    const u16* hcol = h16 + c16*8;
    #pragma unroll
    for (int p=0; p<4; ++p){
      const int iA = p*8 + w;
      const int iB = p*8 + 4 + w;
      const int nA = (int)n0 + iA, nB = (int)n0 + iB;
      const int rsA = rowst[nA], dgA = deg[nA];
      const int rsB = rowst[nB], dgB = deg[nB];
      const int reA = rsA + dgA, reB = rsB + dgB;
      float accA[8] = {0.f,0.f,0.f,0.f,0.f,0.f,0.f,0.f};
      float accB[8] = {0.f,0.f,0.f,0.f,0.f,0.f,0.f,0.f};
      int eA = rsA + g, eB = rsB + g;
      // round 1: 16 edges per node, branchless (99.6% of Poisson(8) nodes)
      {
        const bool a0 = eA    < reA, a1 = eA+4  < reA, a2 = eA+8  < reA, a3 = eA+12 < reA;
        const bool b0 = eB    < reB, b1 = eB+4  < reB, b2 = eB+8  < reB, b3 = eB+12 < reB;
        int sa0 = csr[a0 ? eA    : 0], sa1 = csr[a1 ? eA+4  : 0];
        int sa2 = csr[a2 ? eA+8  : 0], sa3 = csr[a3 ? eA+12 : 0];
        int sb0 = csr[b0 ? eB    : 0], sb1 = csr[b1 ? eB+4  : 0];
        int sb2 = csr[b2 ? eB+8  : 0], sb3 = csr[b3 ? eB+12 : 0];
        uint4 qa0 = *(const uint4*)(hcol + (size_t)sa0*CN);
        uint4 qa1 = *(const uint4*)(hcol + (size_t)sa1*CN);
        uint4 qa2 = *(const uint4*)(hcol + (size_t)sa2*CN);
        uint4 qa3 = *(const uint4*)(hcol + (size_t)sa3*CN);
        uint4 qb0 = *(const uint4*)(hcol + (size_t)sb0*CN);
        uint4 qb1 = *(const uint4*)(hcol + (size_t)sb1*CN);
        uint4 qb2 = *(const uint4*)(hcol + (size_t)sb2*CN);
        uint4 qb3 = *(const uint4*)(hcol + (size_t)sb3*CN);
        unp_fma(accA, qa0, a0?1.f:0.f); unp_fma(accA, qa1, a1?1.f:0.f);
        unp_fma(accA, qa2, a2?1.f:0.f); unp_fma(accA, qa3, a3?1.f:0.f);
        unp_fma(accB, qb0, b0?1.f:0.f); unp_fma(accB, qb1, b1?1.f:0.f);
        unp_fma(accB, qb2, b2?1.f:0.f); unp_fma(accB, qb3, b3?1.f:0.f);
        eA += 16; eB += 16;
      }
      // rare tail: deg > 16 (P ~ 0.4%)
      while (eA < reA || eB < reB){
        const bool a0 = eA < reA, a1 = eA+4 < reA;
        const bool b0 = eB < reB, b1 = eB+4 < reB;
        int sa0 = csr[a0 ? eA   : 0], sa1 = csr[a1 ? eA+4 : 0];
        int sb0 = csr[b0 ? eB   : 0], sb1 = csr[b1 ? eB+4 : 0];
        uint4 qa0 = *(const uint4*)(hcol + (size_t)sa0*CN);
        uint4 qa1 = *(const uint4*)(hcol + (size_t)sa1*CN);
        uint4 qb0 = *(const uint4*)(hcol + (size_t)sb0*CN);
        uint4 qb1 = *(const uint4*)(hcol + (size_t)sb1*CN);
        unp_fma(accA, qa0, a0?1.f:0.f); unp_fma(accA, qa1, a1?1.f:0.f);
        unp_fma(accB, qb0, b0?1.f:0.f); unp_fma(accB, qb1, b1?1.f:0.f);
        eA += 8; eB += 8;
      }
      // fold the 4 edge-slots: lanes {c16, c16+16, c16+32, c16+48} -> all
      #pragma unroll
      for (int j=0;j<8;++j){
        accA[j] += __shfl_xor(accA[j],16); accA[j] += __shfl_xor(accA[j],32);
        accB[j] += __shfl_xor(accB[j],16); accB[j] += __shfl_xor(accB[j],32);
      }
      const float invA = 1.0f / fmaxf((float)dgA, 1.0f);
      const float invB = 1.0f / fmaxf((float)dgB, 1.0f);
      if (g==0){
        u16 ta[8], tb[8];
        #pragma unroll
        for (int j=0;j<8;++j){ ta[j]=f2bf(accA[j]*invA); tb[j]=f2bf(accB[j]*invB); }
        *(uint4*)&sv[iA*136 + c16*8] = *(const uint4*)ta;
        *(uint4*)&sv[iB*136 + c16*8] = *(const uint4*)tb;
      }
    }
  }
  __syncthreads();

  // Phase B: acc = local (sv @ lin_w^T, K=128) + spec (U16 @ ohatT^T, K=64)
  // Both produce the same 32x128 output tile with identical C/D mapping.
  const int rt = w&1, cb = w>>1;
  const int lo16 = lane & 15, qd = (lane>>4)<<3;
  f32x4 acc[4] = {};
  #pragma unroll
  for (int ks=0; ks<4; ++ks){
    short8 af = *(const short8*)&sv[(rt*16 + lo16)*136 + ks*32 + qd];
    #pragma unroll
    for (int c4=0; c4<4; ++c4){
      const short8 bf = *(const short8*)(wsw + ((size_t)((cb*4+c4)*4+ks)*64 + lane)*8);
      acc[c4] = __builtin_amdgcn_mfma_f32_16x16x32_bf16(af, bf, acc[c4], 0, 0, 0);
    }
  }
  {
    const int b = (int)(n0 >> 11);                              // node block -> batch
    const u16* Au = U16  + ((size_t)(n0 + rt*16 + lo16))*MN + qd;
    const u16* Bu = ohatT + ((size_t)(b*CN + cb*64 + lo16))*MN + qd;
    #pragma unroll
    for (int ks=0; ks<2; ++ks){
      short8 af = *(const short8*)(Au + ks*32);
      #pragma unroll
      for (int c4=0; c4<4; ++c4){
        short8 bf = *(const short8*)(Bu + (size_t)c4*16*MN + ks*32);
        acc[c4] = __builtin_amdgcn_mfma_f32_16x16x32_bf16(af, bf, acc[c4], 0, 0, 0);
      }
    }
  }
  #pragma unroll
  for (int c4=0; c4<4; ++c4){
    int col = cb*64 + c4*16 + lo16;
    int rb = rt*16 + ((lane>>4)<<2);
    #pragma unroll
    for (int r=0; r<4; ++r) sx16[(rb+r)*132 + col] = f2bf(acc[c4][r]);
  }
  __syncthreads();

  // Phase C: x = h + (spec+local) + bias; LayerNorm; exact GELU
  float2 lb    = *(const float2*)(lin_b  + 2*lane);
  float2 lg    = *(const float2*)(ln_g   + 2*lane);
  float2 lbe   = *(const float2*)(ln_beta+ 2*lane);
  for (int r=0; r<8; ++r){
    int i = r*4 + w;
    size_t base = (n0 + i)*CN + 2*lane;
    u32 hA = *(const u32*)(h16 + base);
    u32 lA = *(const u32*)&sx16[i*132 + 2*lane];
    float x0 = bf2f((u16)(hA&0xffffu)) + bf2f((u16)(lA&0xffffu)) + lb.x;
    float x1 = bf2f((u16)(hA>>16))     + bf2f((u16)(lA>>16))     + lb.y;
    float s  = x0 + x1;
    float ss = fmaf(x0,x0, x1*x1);
    #pragma unroll
    for (int d=1; d<64; d<<=1){ s += __shfl_xor(s,d); ss += __shfl_xor(ss,d); }
    float mu  = s*(1.0f/128.0f);
    float var = ss*(1.0f/128.0f) - mu*mu;
    float rstd = rsqrtf(var + 1e-5f);
    float xn0 = (x0-mu)*rstd*lg.x + lbe.x;
    float xn1 = (x1-mu)*rstd*lg.y + lbe.y;
    float2 st;
    st.x = 0.5f*xn0*(1.0f + erff(xn0*0.70710678118654752f));
    st.y = 0.5f*xn1*(1.0f + erff(xn1*0.70710678118654752f));
    *(float2*)(out + base) = st;
  }
}

extern "C" void kernel_launch(void* const* d_in, const int* in_sizes, int n_in,
                              void* d_out, int out_size, void* d_ws, size_t ws_size,
                              hipStream_t stream) {
  const float* h      = (const float*)d_in[0];
  const float* U      = (const float*)d_in[1];
  const float* W      = (const float*)d_in[2];
  const float* lin_w  = (const float*)d_in[3];
  const float* lin_b  = (const float*)d_in[4];
  const float* ln_g   = (const float*)d_in[5];
  const float* ln_b2  = (const float*)d_in[6];
  const int* ei       = (const int*)d_in[7];
  const int* src = ei;
  const int* dst = ei + EN;
  float* out = (float*)d_out;

  char* wp = (char*)d_ws;
  float* hp     = (float*)wp; wp += (size_t)8*BN*MN*CN*sizeof(float);    // 16.8 MB
  u16*   ohatT  = (u16*)wp;   wp += (size_t)BN*CN*MN*sizeof(u16);        // 1.05 MB
  u16*   h16    = (u16*)wp;   wp += (size_t)NN*CN*sizeof(u16);           // 33.5 MB
  u16*   ht16   = (u16*)wp;   wp += (size_t)BN*CN*NPGN*sizeof(u16);      // 33.5 MB
  u16*   U16b   = (u16*)wp;   wp += (size_t)BN*NPGN*MN*sizeof(u16);      // 16.8 MB
  u16*   Ut16   = (u16*)wp;   wp += (size_t)BN*MN*NPGN*sizeof(u16);      // 16.8 MB
  u16*   wsw    = (u16*)wp;   wp += (size_t)CN*CN*sizeof(u16);           // 32 KB
  u16*   WT16   = (u16*)wp;   wp += (size_t)MN*CN*CN*sizeof(u16);        // 2.1 MB
  int*   deg    = (int*)wp;   wp += (size_t)NN*sizeof(int);
  int*   rowst  = (int*)wp;   wp += (size_t)NN*sizeof(int);
  int*   cursor = (int*)wp;   wp += (size_t)NN*sizeof(int);
  int*   csr    = (int*)wp;   wp += (size_t)EN*sizeof(int);              // 4.2 MB
  int*   bsum   = (int*)wp;   wp += 512*sizeof(int);
  int*   bofs   = (int*)wp;   wp += 512*sizeof(int);

  hipMemsetAsync(deg,    0, (size_t)NN*sizeof(int), stream);
  hipMemsetAsync(cursor, 0, (size_t)NN*sizeof(int), stream);

  k_count<<<EN/256, 256, 0, stream>>>(dst, deg);
  k_scan1<<<NN/512, 512, 0, stream>>>(deg, rowst, bsum);
  k_scan2<<<1, 256, 0, stream>>>(bsum, bofs);
  k_scan3<<<NN/256, 256, 0, stream>>>(rowst, bofs);
  k_fill<<<EN/256, 256, 0, stream>>>(src, dst, rowst, cursor, csr);

  k_prep_all<<<3080, 256, 0, stream>>>(h, h16, ht16, U, U16b, Ut16, lin_w, wsw);
  k_prepWT<<<MN, 256, 0, stream>>>(W, WT16);

  k_hhat<<<BN*16, 256, 0, stream>>>(Ut16, ht16, hp);
  k_ohat<<<MN*4, 256, 0, stream>>>(hp, WT16, ohatT);

  k_localep<<<NN/32, 256, 0, stream>>>(h16, U16b, ohatT, wsw, rowst, deg, csr,
                                       lin_b, ln_g, ln_b2, out);
}